// Round 1
// baseline (298.107 us; speedup 1.0000x reference)
//
#include <hip/hip_runtime.h>
#include <stdint.h>

#define NVOX 40000
#define CCH  128
#define K2   9
#define NH   5

typedef __attribute__((ext_vector_type(8))) short bf16x8;
typedef __attribute__((ext_vector_type(4))) float f32x4;

__device__ __forceinline__ unsigned short f2b(float f) {
  union { float f; unsigned int u; } v; v.f = f;
  return (unsigned short)((v.u + 0x7fffu + ((v.u >> 16) & 1u)) >> 16);
}
__device__ __forceinline__ float b2f(unsigned short u) {
  union { unsigned int u; float f; } v; v.u = ((unsigned int)u) << 16;
  return v.f;
}
// async global->LDS, 16B per lane; lds dest must be wave-uniform (HW adds lane*16)
__device__ __forceinline__ void g2l16(const void* g, void* l) {
  __builtin_amdgcn_global_load_lds(
      (const __attribute__((address_space(1))) unsigned int*)g,
      (__attribute__((address_space(3))) unsigned int*)l, 16, 0, 0);
}

// ---- convert feats fp32 -> bf16 ----
__global__ void cvt_feats(const float4* __restrict__ in, ushort4* __restrict__ o, int n4) {
  int i = blockIdx.x * 256 + threadIdx.x;
  if (i < n4) {
    float4 v = in[i];
    ushort4 r;
    r.x = f2b(v.x); r.y = f2b(v.y); r.z = f2b(v.z); r.w = f2b(v.w);
    o[i] = r;
  }
}

// ---- convert+transpose W1: [h][k][c][d] fp32 -> [h][k][d][c] bf16 ----
__global__ void cvt_w1(const float* __restrict__ w1, unsigned short* __restrict__ w1t) {
  __shared__ unsigned short t[128 * 34];
  int tile = blockIdx.x;   // h*9+k, 0..44
  int q = blockIdx.y;      // c-quarter 0..3
  const float* src = w1 + (size_t)tile * 16384 + q * 32 * 128;
  for (int e = threadIdx.x; e < 4096; e += 256) {
    int c = e >> 7, d = e & 127;
    t[d * 34 + c] = f2b(src[e]);
  }
  __syncthreads();
  unsigned short* dst = w1t + (size_t)tile * 16384 + q * 32;
  for (int e = threadIdx.x; e < 4096; e += 256) {
    int d = e >> 5, c = e & 31;
    dst[d * 128 + c] = t[d * 34 + c];
  }
}

// ---- gather + GEMM (one head x one 128-row tile per block) + BN partial stats ----
__global__ void __launch_bounds__(256, 2) conv_gemm(
    const unsigned short* __restrict__ fb,   // feats bf16 [N][128]
    const int* __restrict__ nbr,             // [N][9]
    const unsigned short* __restrict__ w1t,  // [H][9][d=128][c=128] bf16
    unsigned short* __restrict__ yb,         // [H][N][128] bf16
    float* __restrict__ sums)                // [2][H][128]
{
  __shared__ unsigned short As[128 * 128];
  __shared__ unsigned short Bs[128 * 128];
  __shared__ int idxs[128 * K2];

  const int h = blockIdx.y;
  const int n0 = blockIdx.x * 128;
  const int tid = threadIdx.x;
  const int wave = tid >> 6;
  const int lane = tid & 63;
  const int lrow = lane >> 4;  // 0..3
  const int lcol = lane & 15;  // 0..15
  const int wm = wave >> 1, wn = wave & 1;

  for (int i = tid; i < 128 * K2; i += 256) {
    int r = i / K2;
    int kk = i - r * K2;
    int gn = n0 + r; if (gn > NVOX - 1) gn = NVOX - 1;
    idxs[i] = nbr[gn * K2 + kk];
  }
  __syncthreads();

  f32x4 acc[4][4] = {};

  for (int k = 0; k < K2; ++k) {
    // stage B (dense 32KB)
    const unsigned short* wp = w1t + (((size_t)h * K2 + k) << 14);
#pragma unroll
    for (int i = 0; i < 8; ++i) {
      int elem = wave * 4096 + i * 512;
      g2l16(wp + elem + lane * 8, &Bs[elem]);
    }
    // stage A (gathered rows, 4 rows per wave-op)
    int ridx[8];
#pragma unroll
    for (int i = 0; i < 8; ++i)
      ridx[i] = idxs[(wave * 32 + i * 4 + lrow) * K2 + k];
#pragma unroll
    for (int i = 0; i < 8; ++i)
      g2l16(fb + (size_t)ridx[i] * CCH + lcol * 8, &As[(wave * 32 + i * 4) * CCH]);

    __syncthreads();
#pragma unroll
    for (int kc = 0; kc < 4; ++kc) {
      bf16x8 af[4], bfr[4];
#pragma unroll
      for (int mi = 0; mi < 4; ++mi)
        af[mi] = *(const bf16x8*)&As[(wm * 64 + mi * 16 + lcol) * CCH + kc * 32 + lrow * 8];
#pragma unroll
      for (int ni = 0; ni < 4; ++ni)
        bfr[ni] = *(const bf16x8*)&Bs[(wn * 64 + ni * 16 + lcol) * CCH + kc * 32 + lrow * 8];
#pragma unroll
      for (int mi = 0; mi < 4; ++mi)
#pragma unroll
        for (int ni = 0; ni < 4; ++ni)
          acc[mi][ni] = __builtin_amdgcn_mfma_f32_16x16x32_bf16(af[mi], bfr[ni], acc[mi][ni], 0, 0, 0);
    }
    __syncthreads();
  }

  // epilogue: acc -> LDS as bf16 (C/D layout: col=lane&15, row=(lane>>4)*4+reg)
#pragma unroll
  for (int mi = 0; mi < 4; ++mi)
#pragma unroll
    for (int ni = 0; ni < 4; ++ni)
#pragma unroll
      for (int r = 0; r < 4; ++r) {
        int row = wm * 64 + mi * 16 + lrow * 4 + r;
        int col = wn * 64 + ni * 16 + lcol;
        As[row * 128 + col] = f2b(acc[mi][ni][r]);
      }
  __syncthreads();

  // coalesced y store
  for (int i = tid; i < 2048; i += 256) {
    int row = i >> 4;
    int col = (i & 15) * 8;
    if (n0 + row < NVOX)
      *(bf16x8*)(yb + ((size_t)h * NVOX + n0 + row) * CCH + col) = *(const bf16x8*)&As[row * 128 + col];
  }

  // BN partial stats over valid rows
  {
    int col = tid & 127, half = tid >> 7;
    int rbase = half * 64;
    int nvalid = NVOX - n0 - rbase;
    if (nvalid > 64) nvalid = 64;
    float s = 0.f, q = 0.f;
    for (int r = 0; r < nvalid; ++r) {
      float z = b2f(As[(rbase + r) * 128 + col]);
      s += z; q += z * z;
    }
    if (nvalid > 0) {
      atomicAdd(&sums[h * CCH + col], s);
      atomicAdd(&sums[NH * CCH + h * CCH + col], q);
    }
  }
}

// ---- finalize BN: scale = rstd*gamma, shift = beta - mean*scale ----
__global__ void finalize_bn(const float* __restrict__ sums, const float* __restrict__ gamma,
                            const float* __restrict__ beta, float* __restrict__ ssb) {
  int h = blockIdx.x, c = threadIdx.x;
  float mean = sums[h * CCH + c] * (1.f / NVOX);
  float var = sums[NH * CCH + h * CCH + c] * (1.f / NVOX) - mean * mean;
  float rstd = rsqrtf(var + 1e-5f);
  float scale = rstd * gamma[h * CCH + c];
  ssb[h * CCH + c] = scale;
  ssb[NH * CCH + h * CCH + c] = beta[h * CCH + c] - mean * scale;
}

// ---- fused BN + ReLU + 5x 1x1 heads + concat ----
__global__ void __launch_bounds__(256) head_fuse(
    const unsigned short* __restrict__ yb, const float* __restrict__ ssb,
    const float* __restrict__ w_hm, const float* __restrict__ b_hm,
    const float* __restrict__ w_ce, const float* __restrict__ b_ce,
    const float* __restrict__ w_cz, const float* __restrict__ b_cz,
    const float* __restrict__ w_dm, const float* __restrict__ b_dm,
    const float* __restrict__ w_rt, const float* __restrict__ b_rt,
    float* __restrict__ out)
{
  int v = blockIdx.x * 256 + threadIdx.x;
  if (v >= NVOX) return;
  float a0 = b_hm[0], a1 = b_hm[1], a2 = b_hm[2];
  float a3 = b_ce[0], a4 = b_ce[1];
  float a5 = b_cz[0];
  float a6 = b_dm[0], a7 = b_dm[1], a8 = b_dm[2];
  float a9 = b_rt[0], a10 = b_rt[1];

#define DO_HEAD(HI, BODY)                                                    \
  {                                                                          \
    const bf16x8* yp = (const bf16x8*)(yb + ((size_t)(HI)*NVOX + v) * CCH);  \
    const float* sc = ssb + (HI)*CCH;                                        \
    const float* sh = ssb + NH * CCH + (HI)*CCH;                             \
    for (int q8 = 0; q8 < 16; ++q8) {                                        \
      bf16x8 pk = yp[q8];                                                    \
      _Pragma("unroll") for (int e = 0; e < 8; ++e) {                        \
        int d = q8 * 8 + e;                                                  \
        float z = fmaf(b2f((unsigned short)pk[e]), sc[d], sh[d]);            \
        z = fmaxf(z, 0.f);                                                   \
        BODY;                                                                \
      }                                                                      \
    }                                                                        \
  }

  DO_HEAD(0, { a0 = fmaf(z, w_hm[d*3+0], a0); a1 = fmaf(z, w_hm[d*3+1], a1); a2 = fmaf(z, w_hm[d*3+2], a2); })
  DO_HEAD(1, { a3 = fmaf(z, w_ce[d*2+0], a3); a4 = fmaf(z, w_ce[d*2+1], a4); })
  DO_HEAD(2, { a5 = fmaf(z, w_cz[d], a5); })
  DO_HEAD(3, { a6 = fmaf(z, w_dm[d*3+0], a6); a7 = fmaf(z, w_dm[d*3+1], a7); a8 = fmaf(z, w_dm[d*3+2], a8); })
  DO_HEAD(4, { a9 = fmaf(z, w_rt[d*2+0], a9); a10 = fmaf(z, w_rt[d*2+1], a10); })
#undef DO_HEAD

  float* op = out + (size_t)v * 11;
  op[0] = a0; op[1] = a1; op[2] = a2; op[3] = a3; op[4] = a4; op[5] = a5;
  op[6] = a6; op[7] = a7; op[8] = a8; op[9] = a9; op[10] = a10;
}

extern "C" void kernel_launch(void* const* d_in, const int* in_sizes, int n_in,
                              void* d_out, int out_size, void* d_ws, size_t ws_size,
                              hipStream_t stream) {
  const float* feats = (const float*)d_in[0];
  const int*   nbr   = (const int*)d_in[1];
  const float* W1    = (const float*)d_in[2];
  const float* gamma = (const float*)d_in[3];
  const float* beta  = (const float*)d_in[4];
  const float* w_hm = (const float*)d_in[5];  const float* b_hm = (const float*)d_in[6];
  const float* w_ce = (const float*)d_in[7];  const float* b_ce = (const float*)d_in[8];
  const float* w_cz = (const float*)d_in[9];  const float* b_cz = (const float*)d_in[10];
  const float* w_dm = (const float*)d_in[11]; const float* b_dm = (const float*)d_in[12];
  const float* w_rt = (const float*)d_in[13]; const float* b_rt = (const float*)d_in[14];
  float* out = (float*)d_out;

  char* ws = (char*)d_ws;
  unsigned short* w1t = (unsigned short*)ws;                   // 11,796,480 B
  unsigned short* fb  = (unsigned short*)(ws + 11796480);      // 10,240,000 B
  unsigned short* yb  = (unsigned short*)(ws + 22036480);      // 51,200,000 B
  float* sums = (float*)(ws + 73236480);                       // 5,120 B
  float* ssb  = (float*)(ws + 73241600);                       // 5,120 B

  hipMemsetAsync(sums, 0, 2 * NH * CCH * sizeof(float), stream);
  cvt_feats<<<5000, 256, 0, stream>>>((const float4*)feats, (ushort4*)fb, NVOX * CCH / 4);
  cvt_w1<<<dim3(45, 4), 256, 0, stream>>>(W1, w1t);
  conv_gemm<<<dim3(313, NH), 256, 0, stream>>>(fb, nbr, w1t, yb, sums);
  finalize_bn<<<NH, CCH, 0, stream>>>(sums, gamma, beta, ssb);
  head_fuse<<<157, 256, 0, stream>>>(yb, ssb, w_hm, b_hm, w_ce, b_ce, w_cz, b_cz,
                                     w_dm, b_dm, w_rt, b_rt, out);
}

// Round 2
// 244.151 us; speedup vs baseline: 1.2210x; 1.2210x over previous
//
#include <hip/hip_runtime.h>
#include <stdint.h>

#define NVOX 40000
#define CCH  128
#define K2   9
#define NH   5

typedef __attribute__((ext_vector_type(8))) short bf16x8;
typedef __attribute__((ext_vector_type(4))) float f32x4;

__device__ __forceinline__ unsigned short f2b(float f) {
  union { float f; unsigned int u; } v; v.f = f;
  return (unsigned short)((v.u + 0x7fffu + ((v.u >> 16) & 1u)) >> 16);
}
__device__ __forceinline__ float b2f(unsigned short u) {
  union { unsigned int u; float f; } v; v.u = ((unsigned int)u) << 16;
  return v.f;
}
// async global->LDS, 16B per lane; lds dest must be wave-uniform (HW adds lane*16)
__device__ __forceinline__ void g2l16(const void* g, void* l) {
  __builtin_amdgcn_global_load_lds(
      (const __attribute__((address_space(1))) unsigned int*)g,
      (__attribute__((address_space(3))) unsigned int*)l, 16, 0, 0);
}
// XOR-swizzled LDS address (in shorts) for logical (row, short-col).
// 16B chunk c of row r stored at chunk c ^ (r&15); banks spread across rows.
__device__ __forceinline__ int swz(int row, int col) {
  return row * 128 + ((((col >> 3) ^ (row & 15)) << 3) | (col & 7));
}

// ---- convert feats fp32 -> bf16 ----
__global__ void cvt_feats(const float4* __restrict__ in, ushort4* __restrict__ o, int n4) {
  int i = blockIdx.x * 256 + threadIdx.x;
  if (i < n4) {
    float4 v = in[i];
    ushort4 r;
    r.x = f2b(v.x); r.y = f2b(v.y); r.z = f2b(v.z); r.w = f2b(v.w);
    o[i] = r;
  }
}

// ---- convert+transpose W1: [h][k][c][d] fp32 -> [h][k][d][c] bf16 ----
__global__ void cvt_w1(const float* __restrict__ w1, unsigned short* __restrict__ w1t) {
  __shared__ unsigned short t[128 * 34];
  int tile = blockIdx.x;   // h*9+k, 0..44
  int q = blockIdx.y;      // c-quarter 0..3
  const float* src = w1 + (size_t)tile * 16384 + q * 32 * 128;
  for (int e = threadIdx.x; e < 4096; e += 256) {
    int c = e >> 7, d = e & 127;
    t[d * 34 + c] = f2b(src[e]);
  }
  __syncthreads();
  unsigned short* dst = w1t + (size_t)tile * 16384 + q * 32;
  for (int e = threadIdx.x; e < 4096; e += 256) {
    int d = e >> 5, c = e & 31;
    dst[d * 128 + c] = t[d * 34 + c];
  }
}

// ---- gather + GEMM (one head x one 128-row tile per block) + BN partial stats ----
__global__ void __launch_bounds__(256, 2) conv_gemm(
    const unsigned short* __restrict__ fb,   // feats bf16 [N][128]
    const int* __restrict__ nbr,             // [N][9]
    const unsigned short* __restrict__ w1t,  // [H][9][d=128][c=128] bf16
    unsigned short* __restrict__ yb,         // [H][N][128] bf16
    float* __restrict__ sums)                // [2][H][128]
{
  __shared__ unsigned short As[128 * 128];
  __shared__ unsigned short Bs[128 * 128];
  __shared__ int idxs[128 * K2];

  const int h = blockIdx.y;
  const int n0 = blockIdx.x * 128;
  const int tid = threadIdx.x;
  const int wave = tid >> 6;
  const int lane = tid & 63;
  const int lrow = lane >> 4;  // 0..3
  const int lcol = lane & 15;  // 0..15
  const int wm = wave >> 1, wn = wave & 1;

  for (int i = tid; i < 128 * K2; i += 256) {
    int r = i / K2;
    int kk = i - r * K2;
    int gn = n0 + r; if (gn > NVOX - 1) gn = NVOX - 1;
    idxs[i] = nbr[gn * K2 + kk];
  }
  __syncthreads();

  f32x4 acc[4][4] = {};

  for (int k = 0; k < K2; ++k) {
    // stage B (dense 32KB); lane lands at row=(elem>>7)+lrow, chunk lcol ->
    // fetch global chunk lcol^(row&15)
    const unsigned short* wp = w1t + (((size_t)h * K2 + k) << 14);
#pragma unroll
    for (int i = 0; i < 8; ++i) {
      int elem = wave * 4096 + i * 512;
      int row = (elem >> 7) + lrow;
      g2l16(wp + row * 128 + ((lcol ^ (row & 15)) << 3), &Bs[elem]);
    }
    // stage A (gathered rows, 4 rows per wave-op), same chunk permutation
    int ridx[8];
#pragma unroll
    for (int i = 0; i < 8; ++i)
      ridx[i] = idxs[(wave * 32 + i * 4 + lrow) * K2 + k];
#pragma unroll
    for (int i = 0; i < 8; ++i) {
      int row = wave * 32 + i * 4 + lrow;
      g2l16(fb + (size_t)ridx[i] * CCH + ((lcol ^ (row & 15)) << 3),
            &As[(wave * 32 + i * 4) * CCH]);
    }

    __syncthreads();
#pragma unroll
    for (int kc = 0; kc < 4; ++kc) {
      bf16x8 af[4], bfr[4];
#pragma unroll
      for (int mi = 0; mi < 4; ++mi) {
        int row = wm * 64 + mi * 16 + lcol;
        af[mi] = *(const bf16x8*)&As[row * CCH + (((kc * 4 + lrow) ^ (row & 15)) << 3)];
      }
#pragma unroll
      for (int ni = 0; ni < 4; ++ni) {
        int row = wn * 64 + ni * 16 + lcol;
        bfr[ni] = *(const bf16x8*)&Bs[row * CCH + (((kc * 4 + lrow) ^ (row & 15)) << 3)];
      }
#pragma unroll
      for (int mi = 0; mi < 4; ++mi)
#pragma unroll
        for (int ni = 0; ni < 4; ++ni)
          acc[mi][ni] = __builtin_amdgcn_mfma_f32_16x16x32_bf16(af[mi], bfr[ni], acc[mi][ni], 0, 0, 0);
    }
    __syncthreads();
  }

  // epilogue: acc -> LDS as bf16 (C/D layout: col=lane&15, row=(lane>>4)*4+reg),
  // swizzled store
#pragma unroll
  for (int mi = 0; mi < 4; ++mi)
#pragma unroll
    for (int ni = 0; ni < 4; ++ni)
#pragma unroll
      for (int r = 0; r < 4; ++r) {
        int row = wm * 64 + mi * 16 + lrow * 4 + r;
        int col = wn * 64 + ni * 16 + lcol;
        As[swz(row, col)] = f2b(acc[mi][ni][r]);
      }
  __syncthreads();

  // coalesced y store (un-swizzle on read)
  for (int i = tid; i < 2048; i += 256) {
    int row = i >> 4;
    int c = i & 15;
    if (n0 + row < NVOX)
      *(bf16x8*)(yb + ((size_t)h * NVOX + n0 + row) * CCH + c * 8) =
          *(const bf16x8*)&As[row * 128 + ((c ^ (row & 15)) << 3)];
  }

  // BN partial stats over valid rows
  {
    int col = tid & 127, half = tid >> 7;
    int rbase = half * 64;
    int nvalid = NVOX - n0 - rbase;
    if (nvalid > 64) nvalid = 64;
    float s = 0.f, q = 0.f;
    for (int r = 0; r < nvalid; ++r) {
      float z = b2f(As[swz(rbase + r, col)]);
      s += z; q += z * z;
    }
    if (nvalid > 0) {
      atomicAdd(&sums[h * CCH + col], s);
      atomicAdd(&sums[NH * CCH + h * CCH + col], q);
    }
  }
}

// ---- finalize BN: scale = rstd*gamma, shift = beta - mean*scale ----
__global__ void finalize_bn(const float* __restrict__ sums, const float* __restrict__ gamma,
                            const float* __restrict__ beta, float* __restrict__ ssb) {
  int h = blockIdx.x, c = threadIdx.x;
  float mean = sums[h * CCH + c] * (1.f / NVOX);
  float var = sums[NH * CCH + h * CCH + c] * (1.f / NVOX) - mean * mean;
  float rstd = rsqrtf(var + 1e-5f);
  float scale = rstd * gamma[h * CCH + c];
  ssb[h * CCH + c] = scale;
  ssb[NH * CCH + h * CCH + c] = beta[h * CCH + c] - mean * scale;
}

// ---- fused BN + ReLU + 5x 1x1 heads + concat ----
__global__ void __launch_bounds__(256) head_fuse(
    const unsigned short* __restrict__ yb, const float* __restrict__ ssb,
    const float* __restrict__ w_hm, const float* __restrict__ b_hm,
    const float* __restrict__ w_ce, const float* __restrict__ b_ce,
    const float* __restrict__ w_cz, const float* __restrict__ b_cz,
    const float* __restrict__ w_dm, const float* __restrict__ b_dm,
    const float* __restrict__ w_rt, const float* __restrict__ b_rt,
    float* __restrict__ out)
{
  int v = blockIdx.x * 256 + threadIdx.x;
  if (v >= NVOX) return;
  float a0 = b_hm[0], a1 = b_hm[1], a2 = b_hm[2];
  float a3 = b_ce[0], a4 = b_ce[1];
  float a5 = b_cz[0];
  float a6 = b_dm[0], a7 = b_dm[1], a8 = b_dm[2];
  float a9 = b_rt[0], a10 = b_rt[1];

#define DO_HEAD(HI, BODY)                                                    \
  {                                                                          \
    const bf16x8* yp = (const bf16x8*)(yb + ((size_t)(HI)*NVOX + v) * CCH);  \
    const float* sc = ssb + (HI)*CCH;                                        \
    const float* sh = ssb + NH * CCH + (HI)*CCH;                             \
    for (int q8 = 0; q8 < 16; ++q8) {                                        \
      bf16x8 pk = yp[q8];                                                    \
      _Pragma("unroll") for (int e = 0; e < 8; ++e) {                        \
        int d = q8 * 8 + e;                                                  \
        float z = fmaf(b2f((unsigned short)pk[e]), sc[d], sh[d]);            \
        z = fmaxf(z, 0.f);                                                   \
        BODY;                                                                \
      }                                                                      \
    }                                                                        \
  }

  DO_HEAD(0, { a0 = fmaf(z, w_hm[d*3+0], a0); a1 = fmaf(z, w_hm[d*3+1], a1); a2 = fmaf(z, w_hm[d*3+2], a2); })
  DO_HEAD(1, { a3 = fmaf(z, w_ce[d*2+0], a3); a4 = fmaf(z, w_ce[d*2+1], a4); })
  DO_HEAD(2, { a5 = fmaf(z, w_cz[d], a5); })
  DO_HEAD(3, { a6 = fmaf(z, w_dm[d*3+0], a6); a7 = fmaf(z, w_dm[d*3+1], a7); a8 = fmaf(z, w_dm[d*3+2], a8); })
  DO_HEAD(4, { a9 = fmaf(z, w_rt[d*2+0], a9); a10 = fmaf(z, w_rt[d*2+1], a10); })
#undef DO_HEAD

  float* op = out + (size_t)v * 11;
  op[0] = a0; op[1] = a1; op[2] = a2; op[3] = a3; op[4] = a4; op[5] = a5;
  op[6] = a6; op[7] = a7; op[8] = a8; op[9] = a9; op[10] = a10;
}

extern "C" void kernel_launch(void* const* d_in, const int* in_sizes, int n_in,
                              void* d_out, int out_size, void* d_ws, size_t ws_size,
                              hipStream_t stream) {
  const float* feats = (const float*)d_in[0];
  const int*   nbr   = (const int*)d_in[1];
  const float* W1    = (const float*)d_in[2];
  const float* gamma = (const float*)d_in[3];
  const float* beta  = (const float*)d_in[4];
  const float* w_hm = (const float*)d_in[5];  const float* b_hm = (const float*)d_in[6];
  const float* w_ce = (const float*)d_in[7];  const float* b_ce = (const float*)d_in[8];
  const float* w_cz = (const float*)d_in[9];  const float* b_cz = (const float*)d_in[10];
  const float* w_dm = (const float*)d_in[11]; const float* b_dm = (const float*)d_in[12];
  const float* w_rt = (const float*)d_in[13]; const float* b_rt = (const float*)d_in[14];
  float* out = (float*)d_out;

  char* ws = (char*)d_ws;
  unsigned short* w1t = (unsigned short*)ws;                   // 11,796,480 B
  unsigned short* fb  = (unsigned short*)(ws + 11796480);      // 10,240,000 B
  unsigned short* yb  = (unsigned short*)(ws + 22036480);      // 51,200,000 B
  float* sums = (float*)(ws + 73236480);                       // 5,120 B
  float* ssb  = (float*)(ws + 73241600);                       // 5,120 B

  hipMemsetAsync(sums, 0, 2 * NH * CCH * sizeof(float), stream);
  cvt_feats<<<5000, 256, 0, stream>>>((const float4*)feats, (ushort4*)fb, NVOX * CCH / 4);
  cvt_w1<<<dim3(45, 4), 256, 0, stream>>>(W1, w1t);
  conv_gemm<<<dim3(313, NH), 256, 0, stream>>>(fb, nbr, w1t, yb, sums);
  finalize_bn<<<NH, CCH, 0, stream>>>(sums, gamma, beta, ssb);
  head_fuse<<<157, 256, 0, stream>>>(yb, ssb, w_hm, b_hm, w_ce, b_ce, w_cz, b_cz,
                                     w_dm, b_dm, w_rt, b_rt, out);
}